// Round 1
// baseline (222.964 us; speedup 1.0000x reference)
//
#include <hip/hip_runtime.h>
#include <math.h>

// Problem constants (fixed by the reference).
#define B_  16
#define N_  16384
#define D_  64
#define K_  64
#define TILE_P 64
#define THREADS 256
#define OUT_PER_B (K_ + 2*K_*D_)   // 8256
#define PART_FLOATS OUT_PER_B      // qsum[64], qx[4096], qx2[4096]

// ws float layout:
//   [0,4096)      coefA_T[d][k] = -0.5/var[k][d]
//   [4096,8192)   coefB_T[d][k] = mu[k][d]/var[k][d]
//   [8192,8256)   c0[k] = log(pi[k]) - 0.5*(D*log(2pi) + sum log var + sum mu^2/var)
//   [8256, ...)   partials: (b*chunks + chunk)*8256 floats each

__global__ __launch_bounds__(256) void fv_prep(const float* __restrict__ pi,
                                               const float* __restrict__ mu,
                                               const float* __restrict__ var,
                                               float* __restrict__ ws) {
    int t = threadIdx.x;
    for (int r = 0; r < 16; ++r) {
        int idx = t + r * 256;            // idx = k*64 + d
        int d = idx & 63;
        int k = idx >> 6;
        float v  = var[idx];
        float m  = mu[idx];
        float iv = 1.0f / v;
        ws[d * 64 + k]        = -0.5f * iv;
        ws[4096 + d * 64 + k] = m * iv;
    }
    if (t < 64) {
        float s = 0.0f;
        for (int d = 0; d < 64; ++d) {
            float v = var[t * 64 + d];
            float m = mu[t * 64 + d];
            s += logf(v) + m * m / v;
        }
        // D*log(2*pi) = 64 * 1.8378770664093453 = 117.6241322501981
        ws[8192 + t] = logf(pi[t]) - 0.5f * (117.624132f + s);
    }
}

__global__ __launch_bounds__(256) void fv_main(const float* __restrict__ x,
                                               const float* __restrict__ ws,
                                               float* __restrict__ partials,
                                               int chunks) {
    __shared__ float c0s[64];
    __shared__ float cAB[8192];              // cA = cAB[0..4096), cB = cAB[4096..8192)
    __shared__ float Xs[64][68];             // pad 64 -> 68 (keeps 16B align, breaks bank stride)
    __shared__ float Qs[64][68];

    const int t     = threadIdx.x;
    const int bi    = blockIdx.y;
    const int chunk = blockIdx.x;

    // stage coefficients
    for (int r = 0; r < 8; ++r) {
        int i4 = t + r * 256;                // [0,2048) float4 over 8192 floats
        ((float4*)cAB)[i4] = ((const float4*)ws)[i4];
    }
    if (t < 64) c0s[t] = ws[8192 + t];

    const int kt1 = t & 15, pt1 = t >> 4;    // phase 1: 4 points x 4 ks per thread
    const int dt2 = t & 15, kt2 = t >> 4;    // phase 2: 4 ks x 4 ds per thread

    float accX[4][4]  = {{0}};
    float accX2[4][4] = {{0}};
    float qsum[4]     = {0};

    const int ppb = N_ / chunks;             // points per block
    const int n0  = chunk * ppb;
    const float* xb = x + ((size_t)bi * N_ + n0) * D_;

    __syncthreads();

    for (int tile = 0; tile < ppb / TILE_P; ++tile) {
        // ---- stage X tile (64 points x 64 dims), coalesced float4 ----
        const float4* xt4 = (const float4*)(xb + (size_t)tile * TILE_P * D_);
        for (int r = 0; r < 4; ++r) {
            int i4 = t + r * 256;            // [0,1024)
            int p  = i4 >> 4;                // 16 float4 per row
            int j  = i4 & 15;
            *(float4*)&Xs[p][4 * j] = xt4[i4];
        }
        __syncthreads();

        // ---- phase 1: scores (64p x 64k), thread tile 4p x 4k ----
        float s[4][4];
        for (int c = 0; c < 4; ++c) {
            float cc = c0s[4 * kt1 + c];
            for (int i = 0; i < 4; ++i) s[i][c] = cc;
        }
        #pragma unroll 4
        for (int d0 = 0; d0 < 64; d0 += 4) {
            float4 xa[4];
            for (int i = 0; i < 4; ++i) xa[i] = *(const float4*)&Xs[4 * pt1 + i][d0];
            float4 Av[4], Bv[4];
            for (int j = 0; j < 4; ++j) {
                Av[j] = *(const float4*)&cAB[(d0 + j) * 64 + 4 * kt1];
                Bv[j] = *(const float4*)&cAB[4096 + (d0 + j) * 64 + 4 * kt1];
            }
            for (int i = 0; i < 4; ++i) {
                const float* xv = &xa[i].x;
                for (int j = 0; j < 4; ++j) {
                    float xx = xv[j];
                    float x2 = xx * xx;
                    const float* ap = &Av[j].x;
                    const float* bp = &Bv[j].x;
                    for (int c = 0; c < 4; ++c) {
                        s[i][c] = fmaf(ap[c], x2, s[i][c]);
                        s[i][c] = fmaf(bp[c], xx, s[i][c]);
                    }
                }
            }
        }

        // ---- softmax over k (16 lanes x 4 each) + write Q tile ----
        for (int i = 0; i < 4; ++i) {
            float m = fmaxf(fmaxf(s[i][0], s[i][1]), fmaxf(s[i][2], s[i][3]));
            m = fmaxf(m, __shfl_xor(m, 1));
            m = fmaxf(m, __shfl_xor(m, 2));
            m = fmaxf(m, __shfl_xor(m, 4));
            m = fmaxf(m, __shfl_xor(m, 8));
            float e0 = __expf(s[i][0] - m);
            float e1 = __expf(s[i][1] - m);
            float e2 = __expf(s[i][2] - m);
            float e3 = __expf(s[i][3] - m);
            float z = e0 + e1 + e2 + e3;
            z += __shfl_xor(z, 1);
            z += __shfl_xor(z, 2);
            z += __shfl_xor(z, 4);
            z += __shfl_xor(z, 8);
            float inv = 1.0f / z;
            float4 q = make_float4(e0 * inv, e1 * inv, e2 * inv, e3 * inv);
            *(float4*)&Qs[4 * pt1 + i][4 * kt1] = q;
        }
        __syncthreads();

        // ---- phase 2: acc[k][d] += Q^T * X (and X^2), thread tile 4k x 4d ----
        #pragma unroll 8
        for (int p = 0; p < TILE_P; ++p) {
            float4 q  = *(const float4*)&Qs[p][4 * kt2];
            float4 xv = *(const float4*)&Xs[p][4 * dt2];
            const float* qa = &q.x;
            const float* xa = &xv.x;
            float x2a[4];
            for (int j = 0; j < 4; ++j) x2a[j] = xa[j] * xa[j];
            for (int c = 0; c < 4; ++c) {
                qsum[c] += qa[c];
                for (int j = 0; j < 4; ++j) {
                    accX[c][j]  = fmaf(qa[c], xa[j],  accX[c][j]);
                    accX2[c][j] = fmaf(qa[c], x2a[j], accX2[c][j]);
                }
            }
        }
        __syncthreads();
    }

    // ---- write partials ----
    float* part = partials + ((size_t)bi * chunks + chunk) * PART_FLOATS;
    if (dt2 == 0) {
        for (int c = 0; c < 4; ++c) part[4 * kt2 + c] = qsum[c];
    }
    for (int c = 0; c < 4; ++c) {
        int k = 4 * kt2 + c;
        *(float4*)&part[64 + k * 64 + 4 * dt2] =
            make_float4(accX[c][0], accX[c][1], accX[c][2], accX[c][3]);
        *(float4*)&part[64 + 4096 + k * 64 + 4 * dt2] =
            make_float4(accX2[c][0], accX2[c][1], accX2[c][2], accX2[c][3]);
    }
}

__global__ __launch_bounds__(256) void fv_finalize(const float* __restrict__ pi,
                                                   const float* __restrict__ mu,
                                                   const float* __restrict__ var,
                                                   const float* __restrict__ partials,
                                                   float* __restrict__ out,
                                                   int chunks) {
    int g = blockIdx.x * 256 + threadIdx.x;
    if (g >= B_ * OUT_PER_B) return;
    int b   = g / OUT_PER_B;
    int pos = g - b * OUT_PER_B;
    const float* base = partials + (size_t)b * chunks * PART_FLOATS;
    const float invN = 1.0f / (float)N_;

    if (pos < 64) {
        float qs = 0.0f;
        for (int c = 0; c < chunks; ++c) qs += base[c * PART_FLOATS + pos];
        out[g] = qs * invN - pi[pos];
    } else if (pos < 64 + 4096) {
        int idx = pos - 64;
        int k = idx >> 6;
        float qs = 0.0f, qx = 0.0f;
        for (int c = 0; c < chunks; ++c) {
            qs += base[c * PART_FLOATS + k];
            qx += base[c * PART_FLOATS + pos];
        }
        out[g] = (qx - qs * mu[idx]) * invN;
    } else {
        int idx = pos - 64 - 4096;
        int k = idx >> 6;
        float qs = 0.0f, qx = 0.0f, qx2 = 0.0f;
        for (int c = 0; c < chunks; ++c) {
            qs  += base[c * PART_FLOATS + k];
            qx  += base[c * PART_FLOATS + 64 + idx];
            qx2 += base[c * PART_FLOATS + pos];
        }
        float m = mu[idx], v = var[idx];
        out[g] = (-qx2 - qs * m * m + qs * v + 2.0f * qx * m) * invN;
    }
}

extern "C" void kernel_launch(void* const* d_in, const int* in_sizes, int n_in,
                              void* d_out, int out_size, void* d_ws, size_t ws_size,
                              hipStream_t stream) {
    const float* x   = (const float*)d_in[0];
    const float* pi  = (const float*)d_in[1];
    const float* mu  = (const float*)d_in[2];
    const float* var = (const float*)d_in[3];
    float* ws = (float*)d_ws;

    int chunks = 32;
    while (chunks > 1 &&
           (size_t)(8256 + (size_t)B_ * chunks * PART_FLOATS) * sizeof(float) > ws_size)
        chunks >>= 1;
    float* partials = ws + 8256;

    fv_prep<<<1, 256, 0, stream>>>(pi, mu, var, ws);
    fv_main<<<dim3(chunks, B_), 256, 0, stream>>>(x, ws, partials, chunks);
    int total = B_ * OUT_PER_B;
    fv_finalize<<<(total + 255) / 256, 256, 0, stream>>>(pi, mu, var, partials,
                                                         (float*)d_out, chunks);
}

// Round 3
// 142.337 us; speedup vs baseline: 1.5664x; 1.5664x over previous
//
#include <hip/hip_runtime.h>
#include <math.h>

// Problem constants (fixed by the reference).
#define B_  16
#define N_  16384
#define D_  64
#define K_  64
#define OUT_PER_B (K_ + 2*K_*D_)   // 8256
#define PART_FLOATS OUT_PER_B      // qsum[64], qx[4096], qx2[4096]

// ws float layout:
//   [0,4096)      Wt bf16 [64 k][128 kd] as 8192 ushorts: kd<64 = -0.5/var, kd>=64 = mu/var
//   [4096,4160)   c0[k] = log(pi[k]) - 0.5*(D*log(2pi) + sum log var + sum mu^2/var)
//   [4160, ...)   partials: (b*chunks + chunk)*8256 floats each
#define WS_C0_OFF   4096
#define WS_PART_OFF 4160

typedef float f32x4 __attribute__((ext_vector_type(4)));
typedef short short8 __attribute__((ext_vector_type(8)));

__device__ __forceinline__ unsigned short f2bf(float f) {
    union { float f; unsigned int u; } v; v.f = f;
    unsigned int r = v.u + 0x7FFFu + ((v.u >> 16) & 1u);   // round-to-nearest-even
    return (unsigned short)(r >> 16);
}

__global__ __launch_bounds__(256) void fv_prep(const float* __restrict__ pi,
                                               const float* __restrict__ mu,
                                               const float* __restrict__ var,
                                               float* __restrict__ ws) {
    int t = threadIdx.x;
    unsigned short* wt = (unsigned short*)ws;
    for (int i = t; i < 4096; i += 256) {        // i = k*64 + d
        int k = i >> 6, d = i & 63;
        float v  = var[i];
        float m  = mu[i];
        float iv = 1.0f / v;
        wt[k * 128 + d]      = f2bf(-0.5f * iv);
        wt[k * 128 + 64 + d] = f2bf(m * iv);
    }
    if (t < 64) {
        float s = 0.0f;
        for (int d = 0; d < 64; ++d) {
            float v = var[t * 64 + d];
            float m = mu[t * 64 + d];
            s += logf(v) + m * m / v;
        }
        // D*log(2*pi) = 117.6241322501981
        ws[WS_C0_OFF + t] = logf(pi[t]) - 0.5f * (117.624132f + s);
    }
}

// MFMA layouts used (16x16x32 bf16, guide-verified):
//   A[m = lane&15][kk = (lane>>4)*8 + j]   (8 contiguous kk -> ds_read_b128)
//   B[kk = (lane>>4)*8 + j][n = lane&15]
//   C/D: col = lane&15, row = 4*(lane>>4) + reg
__global__ __launch_bounds__(256, 4) void fv_main(const float* __restrict__ x,
                                                  const float* __restrict__ ws,
                                                  float* __restrict__ partials,
                                                  int chunks) {
    __shared__ __align__(16) unsigned short WtS[64 * 136];  // stride 136 bf16 (272B)
    __shared__ __align__(16) unsigned short QtS[64 * 72];   // Q^T[k][p], stride 72 bf16 (144B)
    __shared__ float c0s[64];
    __shared__ float qsum_s[4][64];

    const int t    = threadIdx.x;
    const int w    = t >> 6;        // wave 0..3
    const int lane = t & 63;
    const int r16  = lane & 15;
    const int q    = lane >> 4;     // quad 0..3

    // ---- stage Wt + c0 into LDS (once) ----
    // ws Wt region: 8192 ushorts, rows of 128 ushorts = 16 x 16B chunks per row.
    {
        const uint4* src = (const uint4*)ws;            // 1024 x 16B chunks
        for (int i = t; i < 1024; i += 256) {
            int row = i >> 4, u = i & 15;               // FIX (R2 bug): was i>>3 / i&7
            *(uint4*)&WtS[row * 136 + u * 8] = src[i];
        }
        if (t < 64) c0s[t] = ws[WS_C0_OFF + t];
    }

    const int bi    = blockIdx.y;
    const int chunk = blockIdx.x;
    const int ppb   = N_ / chunks;
    const float* xb = x + ((size_t)bi * N_ + (size_t)chunk * ppb) * D_;

    f32x4 accX[4]  = {};       // Qx  : k rows, d col = 16w + r16
    f32x4 accX2[4] = {};       // Qx2
    float qsacc[4][4] = {};    // per-lane Q sums (fixed ks: 16kt + 4q + rr)

    __syncthreads();

    const int ntiles = ppb / 64;
    for (int tile = 0; tile < ntiles; ++tile) {
        const float* xt = xb + (size_t)tile * 64 * D_;

        // ================= phase 1: S^T[k][p] =================
        // wave w supplies B-operand for points p = 16w + r16 (its point group)
        const float* xrow = xt + (16 * w + r16) * D_ + 8 * q;
        float4 va = *(const float4*)(xrow);
        float4 vb = *(const float4*)(xrow + 4);
        float4 vc = *(const float4*)(xrow + 32);
        float4 vd = *(const float4*)(xrow + 36);

        short8 fxa, fxb, fx2a, fx2b;
        {
            const float* pa = &va.x; const float* pb = &vb.x;
            const float* pc = &vc.x; const float* pd = &vd.x;
            #pragma unroll
            for (int j = 0; j < 4; ++j) {
                fxa[j]      = (short)f2bf(pa[j]);
                fxa[j + 4]  = (short)f2bf(pb[j]);
                fxb[j]      = (short)f2bf(pc[j]);
                fxb[j + 4]  = (short)f2bf(pd[j]);
                fx2a[j]     = (short)f2bf(pa[j] * pa[j]);
                fx2a[j + 4] = (short)f2bf(pb[j] * pb[j]);
                fx2b[j]     = (short)f2bf(pc[j] * pc[j]);
                fx2b[j + 4] = (short)f2bf(pd[j] * pd[j]);
            }
        }

        float sc[4][4];
        #pragma unroll
        for (int kt = 0; kt < 4; ++kt) {
            f32x4 a;
            a[0] = c0s[16 * kt + 4 * q + 0];
            a[1] = c0s[16 * kt + 4 * q + 1];
            a[2] = c0s[16 * kt + 4 * q + 2];
            a[3] = c0s[16 * kt + 4 * q + 3];
            const unsigned short* wr = &WtS[(16 * kt + r16) * 136 + 8 * q];
            a = __builtin_amdgcn_mfma_f32_16x16x32_bf16(*(const short8*)(const void*)(wr),      fx2a, a, 0, 0, 0);
            a = __builtin_amdgcn_mfma_f32_16x16x32_bf16(*(const short8*)(const void*)(wr + 32), fx2b, a, 0, 0, 0);
            a = __builtin_amdgcn_mfma_f32_16x16x32_bf16(*(const short8*)(const void*)(wr + 64), fxa,  a, 0, 0, 0);
            a = __builtin_amdgcn_mfma_f32_16x16x32_bf16(*(const short8*)(const void*)(wr + 96), fxb,  a, 0, 0, 0);
            sc[kt][0] = a[0]; sc[kt][1] = a[1]; sc[kt][2] = a[2]; sc[kt][3] = a[3];
        }

        // ---- softmax over k: 16 in-lane values + lanes^16,^32 (same point p) ----
        float mx = sc[0][0];
        #pragma unroll
        for (int kt = 0; kt < 4; ++kt)
            #pragma unroll
            for (int rr = 0; rr < 4; ++rr) mx = fmaxf(mx, sc[kt][rr]);
        mx = fmaxf(mx, __shfl_xor(mx, 16));
        mx = fmaxf(mx, __shfl_xor(mx, 32));
        float z = 0.0f;
        #pragma unroll
        for (int kt = 0; kt < 4; ++kt)
            #pragma unroll
            for (int rr = 0; rr < 4; ++rr) {
                sc[kt][rr] = __expf(sc[kt][rr] - mx);
                z += sc[kt][rr];
            }
        z += __shfl_xor(z, 16);
        z += __shfl_xor(z, 32);
        float inv = 1.0f / z;
        const int p = 16 * w + r16;
        #pragma unroll
        for (int kt = 0; kt < 4; ++kt)
            #pragma unroll
            for (int rr = 0; rr < 4; ++rr) {
                float qv = sc[kt][rr] * inv;
                qsacc[kt][rr] += qv;
                QtS[(16 * kt + 4 * q + rr) * 72 + p] = f2bf(qv);
            }
        __syncthreads();

        // ================= phase 2: Qx[k][d], Qx2[k][d] =================
        // wave w owns d cols 16w..16w+16; B-operand x[p][d] re-read from global (L2-hot)
        const int d = 16 * w + r16;
        const float* xcol = xt + d;
        float vle[2][8];
        #pragma unroll
        for (int c = 0; c < 2; ++c)
            #pragma unroll
            for (int j = 0; j < 8; ++j)
                vle[c][j] = xcol[(32 * c + 8 * q + j) * D_];
        short8 fxp[2], fx2p[2];
        #pragma unroll
        for (int c = 0; c < 2; ++c)
            #pragma unroll
            for (int j = 0; j < 8; ++j) {
                float v = vle[c][j];
                fxp[c][j]  = (short)f2bf(v);
                fx2p[c][j] = (short)f2bf(v * v);
            }
        #pragma unroll
        for (int kt = 0; kt < 4; ++kt) {
            const unsigned short* qr = &QtS[(16 * kt + r16) * 72 + 8 * q];
            short8 aq0 = *(const short8*)(const void*)(qr);
            short8 aq1 = *(const short8*)(const void*)(qr + 32);
            accX[kt]  = __builtin_amdgcn_mfma_f32_16x16x32_bf16(aq0, fxp[0],  accX[kt],  0, 0, 0);
            accX2[kt] = __builtin_amdgcn_mfma_f32_16x16x32_bf16(aq0, fx2p[0], accX2[kt], 0, 0, 0);
            accX[kt]  = __builtin_amdgcn_mfma_f32_16x16x32_bf16(aq1, fxp[1],  accX[kt],  0, 0, 0);
            accX2[kt] = __builtin_amdgcn_mfma_f32_16x16x32_bf16(aq1, fx2p[1], accX2[kt], 0, 0, 0);
        }
        __syncthreads();   // QtS reused next tile
    }

    // ---- write partials ----
    float* part = partials + ((size_t)bi * chunks + chunk) * PART_FLOATS;
    #pragma unroll
    for (int kt = 0; kt < 4; ++kt)
        #pragma unroll
        for (int rr = 0; rr < 4; ++rr) {
            int k = 16 * kt + 4 * q + rr;
            part[64 + k * 64 + 16 * w + r16]        = accX[kt][rr];
            part[64 + 4096 + k * 64 + 16 * w + r16] = accX2[kt][rr];
        }
    #pragma unroll
    for (int kt = 0; kt < 4; ++kt)
        #pragma unroll
        for (int rr = 0; rr < 4; ++rr) {
            float v = qsacc[kt][rr];
            v += __shfl_xor(v, 1);
            v += __shfl_xor(v, 2);
            v += __shfl_xor(v, 4);
            v += __shfl_xor(v, 8);
            if (r16 == 0) qsum_s[w][16 * kt + 4 * q + rr] = v;
        }
    __syncthreads();
    if (t < 64)
        part[t] = qsum_s[0][t] + qsum_s[1][t] + qsum_s[2][t] + qsum_s[3][t];
}

__global__ __launch_bounds__(256) void fv_finalize(const float* __restrict__ pi,
                                                   const float* __restrict__ mu,
                                                   const float* __restrict__ var,
                                                   const float* __restrict__ partials,
                                                   float* __restrict__ out,
                                                   int chunks) {
    int g = blockIdx.x * 256 + threadIdx.x;
    if (g >= B_ * OUT_PER_B) return;
    int b   = g / OUT_PER_B;
    int pos = g - b * OUT_PER_B;
    const float* base = partials + (size_t)b * chunks * PART_FLOATS;
    const float invN = 1.0f / (float)N_;

    if (pos < 64) {
        float qs = 0.0f;
        for (int c = 0; c < chunks; ++c) qs += base[c * PART_FLOATS + pos];
        out[g] = qs * invN - pi[pos];
    } else if (pos < 64 + 4096) {
        int idx = pos - 64;
        int k = idx >> 6;
        float qs = 0.0f, qx = 0.0f;
        for (int c = 0; c < chunks; ++c) {
            qs += base[c * PART_FLOATS + k];
            qx += base[c * PART_FLOATS + pos];
        }
        out[g] = (qx - qs * mu[idx]) * invN;
    } else {
        int idx = pos - 64 - 4096;
        int k = idx >> 6;
        float qs = 0.0f, qx = 0.0f, qx2 = 0.0f;
        for (int c = 0; c < chunks; ++c) {
            qs  += base[c * PART_FLOATS + k];
            qx  += base[c * PART_FLOATS + 64 + idx];
            qx2 += base[c * PART_FLOATS + pos];
        }
        float m = mu[idx], v = var[idx];
        out[g] = (-qx2 - qs * m * m + qs * v + 2.0f * qx * m) * invN;
    }
}

extern "C" void kernel_launch(void* const* d_in, const int* in_sizes, int n_in,
                              void* d_out, int out_size, void* d_ws, size_t ws_size,
                              hipStream_t stream) {
    const float* x   = (const float*)d_in[0];
    const float* pi  = (const float*)d_in[1];
    const float* mu  = (const float*)d_in[2];
    const float* var = (const float*)d_in[3];
    float* ws = (float*)d_ws;

    int chunks = 64;
    while (chunks > 1 &&
           (size_t)(WS_PART_OFF + (size_t)B_ * chunks * PART_FLOATS) * sizeof(float) > ws_size)
        chunks >>= 1;
    float* partials = ws + WS_PART_OFF;

    fv_prep<<<1, 256, 0, stream>>>(pi, mu, var, ws);
    fv_main<<<dim3(chunks, B_), 256, 0, stream>>>(x, ws, partials, chunks);
    int total = B_ * OUT_PER_B;
    fv_finalize<<<(total + 255) / 256, 256, 0, stream>>>(pi, mu, var, partials,
                                                         (float*)d_out, chunks);
}

// Round 4
// 134.519 us; speedup vs baseline: 1.6575x; 1.0581x over previous
//
#include <hip/hip_runtime.h>
#include <hip/hip_bf16.h>
#include <math.h>

// Problem constants (fixed by the reference).
#define B_  16
#define N_  16384
#define D_  64
#define K_  64
#define OUT_PER_B (K_ + 2*K_*D_)   // 8256
#define PART_FLOATS OUT_PER_B      // qsum[64], qx[4096], qx2[4096]
#define CHUNKS 32

// ws float layout:
//   [0,4096)      Wt bf16 [64 k][128 kd] as 8192 ushorts: kd<64 = -0.5/var, kd>=64 = mu/var
//   [4096,4160)   c0[k] = log(pi[k]) - 0.5*(D*log(2pi) + sum log var + sum mu^2/var)
//   [4160, ...)   partials: (b*chunks + chunk)*8256 floats each
#define WS_C0_OFF   4096
#define WS_PART_OFF 4160

typedef float f32x4 __attribute__((ext_vector_type(4)));
typedef short short8 __attribute__((ext_vector_type(8)));

union U8 { short8 s8; unsigned int u[4]; };

__device__ __forceinline__ unsigned short f2bf(float f) {
    union { float f; unsigned int u; } v; v.f = f;
    unsigned int r = v.u + 0x7FFFu + ((v.u >> 16) & 1u);   // round-to-nearest-even
    return (unsigned short)(r >> 16);
}

// packed RNE f32x2 -> bf16x2 (v_cvt_pk_bf16_f32 on gfx950)
__device__ __forceinline__ unsigned int f2bf2(float lo, float hi) {
    __hip_bfloat162 h = __float22bfloat162_rn(make_float2(lo, hi));
    unsigned int u;
    __builtin_memcpy(&u, &h, 4);
    return u;
}

__global__ __launch_bounds__(256) void fv_prep(const float* __restrict__ pi,
                                               const float* __restrict__ mu,
                                               const float* __restrict__ var,
                                               float* __restrict__ ws) {
    int t = threadIdx.x;
    unsigned short* wt = (unsigned short*)ws;
    for (int i = t; i < 4096; i += 256) {        // i = k*64 + d
        int k = i >> 6, d = i & 63;
        float v  = var[i];
        float m  = mu[i];
        float iv = 1.0f / v;
        wt[k * 128 + d]      = f2bf(-0.5f * iv);
        wt[k * 128 + 64 + d] = f2bf(m * iv);
    }
    if (t < 64) {
        float s = 0.0f;
        for (int d = 0; d < 64; ++d) {
            float v = var[t * 64 + d];
            float m = mu[t * 64 + d];
            s += logf(v) + m * m / v;
        }
        // D*log(2*pi) = 117.6241322501981
        ws[WS_C0_OFF + t] = logf(pi[t]) - 0.5f * (117.624132f + s);
    }
}

// MFMA layouts (16x16x32 bf16, guide-verified):
//   A[m = lane&15][kk = (lane>>4)*8 + j]
//   B[kk = (lane>>4)*8 + j][n = lane&15]
//   C/D: col = lane&15, row = 4*(lane>>4) + reg
__global__ __launch_bounds__(256, 2) void fv_main(const float* __restrict__ x,
                                                  const float* __restrict__ ws,
                                                  float* __restrict__ partials,
                                                  int chunks) {
    __shared__ __align__(16) unsigned short QtS[64 * 72];   // Q^T[k][p], stride 72 bf16
    __shared__ float qsum_s[4][64];

    const int t    = threadIdx.x;
    const int w    = t >> 6;        // wave 0..3
    const int lane = t & 63;
    const int r16  = lane & 15;
    const int q    = lane >> 4;     // quad 0..3

    // ---- tile-invariant operands -> registers (R4: was LDS, ~300 cyc/wave-tile) ----
    short8 wfrag[4][4];             // [kt][half]: A-fragments of Wt
    f32x4  c0v[4];
    {
        const unsigned short* wsu = (const unsigned short*)ws;
        #pragma unroll
        for (int kt = 0; kt < 4; ++kt) {
            const unsigned short* wr = wsu + (16 * kt + r16) * 128 + 8 * q;
            #pragma unroll
            for (int h = 0; h < 4; ++h)
                wfrag[kt][h] = *(const short8*)(const void*)(wr + 32 * h);
            c0v[kt] = *(const f32x4*)(ws + WS_C0_OFF + 16 * kt + 4 * q);
        }
    }

    const int bi    = blockIdx.y;
    const int chunk = blockIdx.x;
    const int ppb   = N_ / chunks;
    const float* xb = x + ((size_t)bi * N_ + (size_t)chunk * ppb) * D_;

    f32x4 accX[4]  = {};       // Qx  : k rows, d col = 16w + r16
    f32x4 accX2[4] = {};       // Qx2
    float qsacc[4][4] = {};    // per-lane Q sums (ks: 16kt + 4q + rr)

    const int ntiles = ppb / 64;
    for (int tile = 0; tile < ntiles; ++tile) {
        const float* xt = xb + (size_t)tile * 64 * D_;

        // ================= phase 1: S^T[k][p] =================
        // wave w supplies B-operand for points p = 16w + r16
        const float* xrow = xt + (16 * w + r16) * D_ + 8 * q;
        float4 va = *(const float4*)(xrow);
        float4 vb = *(const float4*)(xrow + 4);
        float4 vc = *(const float4*)(xrow + 32);
        float4 vd = *(const float4*)(xrow + 36);

        U8 fxa, fxb, fx2a, fx2b;
        fxa.u[0]  = f2bf2(va.x, va.y);           fxa.u[1]  = f2bf2(va.z, va.w);
        fxa.u[2]  = f2bf2(vb.x, vb.y);           fxa.u[3]  = f2bf2(vb.z, vb.w);
        fxb.u[0]  = f2bf2(vc.x, vc.y);           fxb.u[1]  = f2bf2(vc.z, vc.w);
        fxb.u[2]  = f2bf2(vd.x, vd.y);           fxb.u[3]  = f2bf2(vd.z, vd.w);
        fx2a.u[0] = f2bf2(va.x*va.x, va.y*va.y); fx2a.u[1] = f2bf2(va.z*va.z, va.w*va.w);
        fx2a.u[2] = f2bf2(vb.x*vb.x, vb.y*vb.y); fx2a.u[3] = f2bf2(vb.z*vb.z, vb.w*vb.w);
        fx2b.u[0] = f2bf2(vc.x*vc.x, vc.y*vc.y); fx2b.u[1] = f2bf2(vc.z*vc.z, vc.w*vc.w);
        fx2b.u[2] = f2bf2(vd.x*vd.x, vd.y*vd.y); fx2b.u[3] = f2bf2(vd.z*vd.z, vd.w*vd.w);

        float sc[4][4];
        #pragma unroll
        for (int kt = 0; kt < 4; ++kt) {
            f32x4 a = c0v[kt];
            a = __builtin_amdgcn_mfma_f32_16x16x32_bf16(wfrag[kt][0], fx2a.s8, a, 0, 0, 0);
            a = __builtin_amdgcn_mfma_f32_16x16x32_bf16(wfrag[kt][1], fx2b.s8, a, 0, 0, 0);
            a = __builtin_amdgcn_mfma_f32_16x16x32_bf16(wfrag[kt][2], fxa.s8,  a, 0, 0, 0);
            a = __builtin_amdgcn_mfma_f32_16x16x32_bf16(wfrag[kt][3], fxb.s8,  a, 0, 0, 0);
            sc[kt][0] = a[0]; sc[kt][1] = a[1]; sc[kt][2] = a[2]; sc[kt][3] = a[3];
        }

        // ---- softmax over k: 16 in-lane values + lanes^16,^32 (same point p) ----
        float mx = sc[0][0];
        #pragma unroll
        for (int kt = 0; kt < 4; ++kt)
            #pragma unroll
            for (int rr = 0; rr < 4; ++rr) mx = fmaxf(mx, sc[kt][rr]);
        mx = fmaxf(mx, __shfl_xor(mx, 16));
        mx = fmaxf(mx, __shfl_xor(mx, 32));
        float z = 0.0f;
        #pragma unroll
        for (int kt = 0; kt < 4; ++kt)
            #pragma unroll
            for (int rr = 0; rr < 4; ++rr) {
                sc[kt][rr] = __expf(sc[kt][rr] - mx);
                z += sc[kt][rr];
            }
        z += __shfl_xor(z, 16);
        z += __shfl_xor(z, 32);
        float inv = 1.0f / z;
        const int p = 16 * w + r16;
        #pragma unroll
        for (int kt = 0; kt < 4; ++kt) {
            #pragma unroll
            for (int rr = 0; rr < 4; ++rr) {
                float qv = sc[kt][rr] * inv;
                qsacc[kt][rr] += qv;
                QtS[(16 * kt + 4 * q + rr) * 72 + p] = f2bf(qv);
            }
        }

        // phase-2 x loads: independent of QtS, issue before the barrier
        const int dcol = 16 * w + r16;
        const float* xcol = xt + dcol;
        float vle[16];
        #pragma unroll
        for (int c = 0; c < 2; ++c)
            #pragma unroll
            for (int j = 0; j < 8; ++j)
                vle[8 * c + j] = xcol[(32 * c + 8 * q + j) * D_];

        __syncthreads();

        // ================= phase 2: Qx[k][d], Qx2[k][d] =================
        U8 fxp0, fxp1, fx2p0, fx2p1;
        #pragma unroll
        for (int i = 0; i < 4; ++i) {
            float a0 = vle[2 * i], a1 = vle[2 * i + 1];
            float b0 = vle[8 + 2 * i], b1 = vle[8 + 2 * i + 1];
            fxp0.u[i]  = f2bf2(a0, a1);
            fxp1.u[i]  = f2bf2(b0, b1);
            fx2p0.u[i] = f2bf2(a0 * a0, a1 * a1);
            fx2p1.u[i] = f2bf2(b0 * b0, b1 * b1);
        }
        #pragma unroll
        for (int kt = 0; kt < 4; ++kt) {
            const unsigned short* qr = &QtS[(16 * kt + r16) * 72 + 8 * q];
            short8 aq0 = *(const short8*)(const void*)(qr);
            short8 aq1 = *(const short8*)(const void*)(qr + 32);
            accX[kt]  = __builtin_amdgcn_mfma_f32_16x16x32_bf16(aq0, fxp0.s8,  accX[kt],  0, 0, 0);
            accX2[kt] = __builtin_amdgcn_mfma_f32_16x16x32_bf16(aq0, fx2p0.s8, accX2[kt], 0, 0, 0);
            accX[kt]  = __builtin_amdgcn_mfma_f32_16x16x32_bf16(aq1, fxp1.s8,  accX[kt],  0, 0, 0);
            accX2[kt] = __builtin_amdgcn_mfma_f32_16x16x32_bf16(aq1, fx2p1.s8, accX2[kt], 0, 0, 0);
        }
        __syncthreads();   // QtS reused next tile
    }

    // ---- write partials ----
    float* part = partials + ((size_t)bi * chunks + chunk) * PART_FLOATS;
    #pragma unroll
    for (int kt = 0; kt < 4; ++kt)
        #pragma unroll
        for (int rr = 0; rr < 4; ++rr) {
            int k = 16 * kt + 4 * q + rr;
            part[64 + k * 64 + 16 * w + r16]        = accX[kt][rr];
            part[64 + 4096 + k * 64 + 16 * w + r16] = accX2[kt][rr];
        }
    #pragma unroll
    for (int kt = 0; kt < 4; ++kt)
        #pragma unroll
        for (int rr = 0; rr < 4; ++rr) {
            float v = qsacc[kt][rr];
            v += __shfl_xor(v, 1);
            v += __shfl_xor(v, 2);
            v += __shfl_xor(v, 4);
            v += __shfl_xor(v, 8);
            if (r16 == 0) qsum_s[w][16 * kt + 4 * q + rr] = v;
        }
    __syncthreads();
    if (t < 64)
        part[t] = qsum_s[0][t] + qsum_s[1][t] + qsum_s[2][t] + qsum_s[3][t];
}

__global__ __launch_bounds__(256) void fv_finalize(const float* __restrict__ pi,
                                                   const float* __restrict__ mu,
                                                   const float* __restrict__ var,
                                                   const float* __restrict__ partials,
                                                   float* __restrict__ out,
                                                   int chunks) {
    int g = blockIdx.x * 256 + threadIdx.x;
    if (g >= B_ * OUT_PER_B) return;
    int b   = g / OUT_PER_B;
    int pos = g - b * OUT_PER_B;
    const float* base = partials + (size_t)b * chunks * PART_FLOATS;
    const float invN = 1.0f / (float)N_;

    if (pos < 64) {
        float qs = 0.0f;
        for (int c = 0; c < chunks; ++c) qs += base[c * PART_FLOATS + pos];
        out[g] = qs * invN - pi[pos];
    } else if (pos < 64 + 4096) {
        int idx = pos - 64;
        int k = idx >> 6;
        float qs = 0.0f, qx = 0.0f;
        for (int c = 0; c < chunks; ++c) {
            qs += base[c * PART_FLOATS + k];
            qx += base[c * PART_FLOATS + pos];
        }
        out[g] = (qx - qs * mu[idx]) * invN;
    } else {
        int idx = pos - 64 - 4096;
        int k = idx >> 6;
        float qs = 0.0f, qx = 0.0f, qx2 = 0.0f;
        for (int c = 0; c < chunks; ++c) {
            qs  += base[c * PART_FLOATS + k];
            qx  += base[c * PART_FLOATS + 64 + idx];
            qx2 += base[c * PART_FLOATS + pos];
        }
        float m = mu[idx], v = var[idx];
        out[g] = (-qx2 - qs * m * m + qs * v + 2.0f * qx * m) * invN;
    }
}

extern "C" void kernel_launch(void* const* d_in, const int* in_sizes, int n_in,
                              void* d_out, int out_size, void* d_ws, size_t ws_size,
                              hipStream_t stream) {
    const float* x   = (const float*)d_in[0];
    const float* pi  = (const float*)d_in[1];
    const float* mu  = (const float*)d_in[2];
    const float* var = (const float*)d_in[3];
    float* ws = (float*)d_ws;

    int chunks = CHUNKS;
    while (chunks > 1 &&
           (size_t)(WS_PART_OFF + (size_t)B_ * chunks * PART_FLOATS) * sizeof(float) > ws_size)
        chunks >>= 1;
    float* partials = ws + WS_PART_OFF;

    fv_prep<<<1, 256, 0, stream>>>(pi, mu, var, ws);
    fv_main<<<dim3(chunks, B_), 256, 0, stream>>>(x, ws, partials, chunks);
    int total = B_ * OUT_PER_B;
    fv_finalize<<<(total + 255) / 256, 256, 0, stream>>>(pi, mu, var, partials,
                                                         (float*)d_out, chunks);
}

// Round 5
// 128.250 us; speedup vs baseline: 1.7385x; 1.0489x over previous
//
#include <hip/hip_runtime.h>
#include <hip/hip_bf16.h>
#include <math.h>

// Problem constants (fixed by the reference).
#define B_  16
#define N_  16384
#define D_  64
#define K_  64
#define OUT_PER_B (K_ + 2*K_*D_)   // 8256
#define PART_FLOATS OUT_PER_B      // qsum[64], qx[4096], qx2[4096]
#define CHUNKS 32
#define NTILES (N_ / CHUNKS / 64)  // 8

// ws float layout:
//   [0,4096)      Wt bf16 [64 k][128 kd] as 8192 ushorts: kd<64 = -0.5/var, kd>=64 = mu/var
//   [4096,4160)   c0[k] = log(pi[k]) - 0.5*(D*log(2pi) + sum log var + sum mu^2/var)
//   [4160, ...)   partials: (b*chunks + chunk)*8256 floats each
#define WS_C0_OFF   4096
#define WS_PART_OFF 4160

typedef float f32x4 __attribute__((ext_vector_type(4)));
typedef short short8 __attribute__((ext_vector_type(8)));

union U8 { short8 s8; unsigned int u[4]; };

__device__ __forceinline__ unsigned short f2bf(float f) {
    union { float f; unsigned int u; } v; v.f = f;
    unsigned int r = v.u + 0x7FFFu + ((v.u >> 16) & 1u);   // round-to-nearest-even
    return (unsigned short)(r >> 16);
}

// packed RNE f32x2 -> bf16x2 (v_cvt_pk_bf16_f32 on gfx950)
__device__ __forceinline__ unsigned int f2bf2(float lo, float hi) {
    __hip_bfloat162 h = __float22bfloat162_rn(make_float2(lo, hi));
    unsigned int u;
    __builtin_memcpy(&u, &h, 4);
    return u;
}

__global__ __launch_bounds__(256) void fv_prep(const float* __restrict__ pi,
                                               const float* __restrict__ mu,
                                               const float* __restrict__ var,
                                               float* __restrict__ ws) {
    __shared__ float red[256];
    int t = threadIdx.x;
    unsigned short* wt = (unsigned short*)ws;
    for (int i = t; i < 4096; i += 256) {        // i = k*64 + d
        int k = i >> 6, d = i & 63;
        float v  = var[i];
        float m  = mu[i];
        float iv = 1.0f / v;
        wt[k * 128 + d]      = f2bf(-0.5f * iv);
        wt[k * 128 + 64 + d] = f2bf(m * iv);
    }
    // c0: 4 threads per k, 16 dims each (R5: was 64 serial logf on one wave)
    int k = t >> 2, pr = t & 3;
    float s = 0.0f;
    #pragma unroll
    for (int j = 0; j < 16; ++j) {
        int d = pr * 16 + j;
        float v = var[k * 64 + d];
        float m = mu[k * 64 + d];
        s += __logf(v) + m * m / v;
    }
    red[t] = s;
    __syncthreads();
    if (pr == 0) {
        float sum = red[4 * k] + red[4 * k + 1] + red[4 * k + 2] + red[4 * k + 3];
        // D*log(2*pi) = 117.6241322501981
        ws[WS_C0_OFF + k] = __logf(pi[k]) - 0.5f * (117.6241322502f + sum);
    }
}

// MFMA layouts (16x16x32 bf16, guide-verified):
//   A[m = lane&15][kk = (lane>>4)*8 + j]
//   B[kk = (lane>>4)*8 + j][n = lane&15]
//   C/D: col = lane&15, row = 4*(lane>>4) + reg
__global__ __launch_bounds__(256, 2) void fv_main(const float* __restrict__ x,
                                                  const float* __restrict__ ws,
                                                  float* __restrict__ partials) {
    __shared__ __align__(16) unsigned short QtS[2][64 * 72];  // double-buffered Q^T[k][p]
    __shared__ float qsum_s[4][64];

    const int t    = threadIdx.x;
    const int w    = t >> 6;        // wave 0..3
    const int lane = t & 63;
    const int r16  = lane & 15;
    const int q    = lane >> 4;     // quad 0..3

    // ---- tile-invariant operands -> registers ----
    short8 wfrag[4][4];             // [kt][half]: A-fragments of Wt
    f32x4  c0v[4];
    {
        const unsigned short* wsu = (const unsigned short*)ws;
        #pragma unroll
        for (int kt = 0; kt < 4; ++kt) {
            const unsigned short* wr = wsu + (16 * kt + r16) * 128 + 8 * q;
            #pragma unroll
            for (int h = 0; h < 4; ++h)
                wfrag[kt][h] = *(const short8*)(const void*)(wr + 32 * h);
            c0v[kt] = *(const f32x4*)(ws + WS_C0_OFF + 16 * kt + 4 * q);
        }
    }

    const int bi    = blockIdx.y;
    const int chunk = blockIdx.x;
    const int ppb   = N_ / CHUNKS;
    const float* xb = x + ((size_t)bi * N_ + (size_t)chunk * ppb) * D_;

    f32x4 accX[4]  = {};       // Qx  : k rows, d col = 16w + r16
    f32x4 accX2[4] = {};       // Qx2
    float qsacc[4][4] = {};    // per-lane Q sums (ks: 16kt + 4q + rr)

    const int rowoff = (16 * w + r16) * D_ + 8 * q;   // phase-1 row base
    const int dcol   = 16 * w + r16;                  // phase-2 column

    // ---- preload tile 0 (phase-1 rows + phase-2 columns) ----
    float4 va, vb, vc, vd;
    float  vle[16];
    {
        const float* xr = xb + rowoff;
        va = *(const float4*)(xr);
        vb = *(const float4*)(xr + 4);
        vc = *(const float4*)(xr + 32);
        vd = *(const float4*)(xr + 36);
        const float* xc = xb + dcol;
        #pragma unroll
        for (int c = 0; c < 2; ++c)
            #pragma unroll
            for (int j = 0; j < 8; ++j)
                vle[8 * c + j] = xc[(32 * c + 8 * q + j) * D_];
    }

    #pragma unroll 2
    for (int tile = 0; tile < NTILES; ++tile) {
        // ---- prefetch tile+1 NOW: ~500 cyc of phase-1 compute hides the latency,
        //      so the vmcnt(0) drain at the (single) barrier is nearly free ----
        float4 nva, nvb, nvc, nvd;
        float  nvle[16];
        if (tile + 1 < NTILES) {
            const float* xtn = xb + (size_t)(tile + 1) * 64 * D_;
            const float* xr = xtn + rowoff;
            nva = *(const float4*)(xr);
            nvb = *(const float4*)(xr + 4);
            nvc = *(const float4*)(xr + 32);
            nvd = *(const float4*)(xr + 36);
            const float* xc = xtn + dcol;
            #pragma unroll
            for (int c = 0; c < 2; ++c)
                #pragma unroll
                for (int j = 0; j < 8; ++j)
                    nvle[8 * c + j] = xc[(32 * c + 8 * q + j) * D_];
        }

        // ================= phase 1: S^T[k][p] =================
        U8 fxa, fxb, fx2a, fx2b;
        fxa.u[0]  = f2bf2(va.x, va.y);           fxa.u[1]  = f2bf2(va.z, va.w);
        fxa.u[2]  = f2bf2(vb.x, vb.y);           fxa.u[3]  = f2bf2(vb.z, vb.w);
        fxb.u[0]  = f2bf2(vc.x, vc.y);           fxb.u[1]  = f2bf2(vc.z, vc.w);
        fxb.u[2]  = f2bf2(vd.x, vd.y);           fxb.u[3]  = f2bf2(vd.z, vd.w);
        fx2a.u[0] = f2bf2(va.x*va.x, va.y*va.y); fx2a.u[1] = f2bf2(va.z*va.z, va.w*va.w);
        fx2a.u[2] = f2bf2(vb.x*vb.x, vb.y*vb.y); fx2a.u[3] = f2bf2(vb.z*vb.z, vb.w*vb.w);
        fx2b.u[0] = f2bf2(vc.x*vc.x, vc.y*vc.y); fx2b.u[1] = f2bf2(vc.z*vc.z, vc.w*vc.w);
        fx2b.u[2] = f2bf2(vd.x*vd.x, vd.y*vd.y); fx2b.u[3] = f2bf2(vd.z*vd.z, vd.w*vd.w);

        float sc[4][4];
        #pragma unroll
        for (int kt = 0; kt < 4; ++kt) {
            f32x4 a = c0v[kt];
            a = __builtin_amdgcn_mfma_f32_16x16x32_bf16(wfrag[kt][0], fx2a.s8, a, 0, 0, 0);
            a = __builtin_amdgcn_mfma_f32_16x16x32_bf16(wfrag[kt][1], fx2b.s8, a, 0, 0, 0);
            a = __builtin_amdgcn_mfma_f32_16x16x32_bf16(wfrag[kt][2], fxa.s8,  a, 0, 0, 0);
            a = __builtin_amdgcn_mfma_f32_16x16x32_bf16(wfrag[kt][3], fxb.s8,  a, 0, 0, 0);
            sc[kt][0] = a[0]; sc[kt][1] = a[1]; sc[kt][2] = a[2]; sc[kt][3] = a[3];
        }

        // ---- softmax over k: 16 in-lane values + lanes^16,^32 (same point p) ----
        float mx = sc[0][0];
        #pragma unroll
        for (int kt = 0; kt < 4; ++kt)
            #pragma unroll
            for (int rr = 0; rr < 4; ++rr) mx = fmaxf(mx, sc[kt][rr]);
        mx = fmaxf(mx, __shfl_xor(mx, 16));
        mx = fmaxf(mx, __shfl_xor(mx, 32));
        float z = 0.0f;
        #pragma unroll
        for (int kt = 0; kt < 4; ++kt)
            #pragma unroll
            for (int rr = 0; rr < 4; ++rr) {
                sc[kt][rr] = __expf(sc[kt][rr] - mx);
                z += sc[kt][rr];
            }
        z += __shfl_xor(z, 16);
        z += __shfl_xor(z, 32);
        float inv = 1.0f / z;
        const int p = 16 * w + r16;
        unsigned short* Qb = QtS[tile & 1];
        #pragma unroll
        for (int kt = 0; kt < 4; ++kt) {
            #pragma unroll
            for (int rr = 0; rr < 4; ++rr) {
                float qv = sc[kt][rr] * inv;
                qsacc[kt][rr] += qv;
                Qb[(16 * kt + 4 * q + rr) * 72 + p] = f2bf(qv);
            }
        }

        __syncthreads();   // the ONLY barrier per tile (QtS double-buffered)

        // ================= phase 2: Qx[k][d], Qx2[k][d] =================
        U8 fxp0, fxp1, fx2p0, fx2p1;
        #pragma unroll
        for (int i = 0; i < 4; ++i) {
            float a0 = vle[2 * i], a1 = vle[2 * i + 1];
            float b0 = vle[8 + 2 * i], b1 = vle[8 + 2 * i + 1];
            fxp0.u[i]  = f2bf2(a0, a1);
            fxp1.u[i]  = f2bf2(b0, b1);
            fx2p0.u[i] = f2bf2(a0 * a0, a1 * a1);
            fx2p1.u[i] = f2bf2(b0 * b0, b1 * b1);
        }
        #pragma unroll
        for (int kt = 0; kt < 4; ++kt) {
            const unsigned short* qr = &Qb[(16 * kt + r16) * 72 + 8 * q];
            short8 aq0 = *(const short8*)(const void*)(qr);
            short8 aq1 = *(const short8*)(const void*)(qr + 32);
            accX[kt]  = __builtin_amdgcn_mfma_f32_16x16x32_bf16(aq0, fxp0.s8,  accX[kt],  0, 0, 0);
            accX2[kt] = __builtin_amdgcn_mfma_f32_16x16x32_bf16(aq0, fx2p0.s8, accX2[kt], 0, 0, 0);
            accX[kt]  = __builtin_amdgcn_mfma_f32_16x16x32_bf16(aq1, fxp1.s8,  accX[kt],  0, 0, 0);
            accX2[kt] = __builtin_amdgcn_mfma_f32_16x16x32_bf16(aq1, fx2p1.s8, accX2[kt], 0, 0, 0);
        }

        // rotate pipeline registers (renamed away by unroll)
        va = nva; vb = nvb; vc = nvc; vd = nvd;
        #pragma unroll
        for (int i = 0; i < 16; ++i) vle[i] = nvle[i];
    }

    // ---- write partials ----
    float* part = partials + ((size_t)bi * CHUNKS + chunk) * PART_FLOATS;
    #pragma unroll
    for (int kt = 0; kt < 4; ++kt)
        #pragma unroll
        for (int rr = 0; rr < 4; ++rr) {
            int k = 16 * kt + 4 * q + rr;
            part[64 + k * 64 + 16 * w + r16]        = accX[kt][rr];
            part[64 + 4096 + k * 64 + 16 * w + r16] = accX2[kt][rr];
        }
    #pragma unroll
    for (int kt = 0; kt < 4; ++kt)
        #pragma unroll
        for (int rr = 0; rr < 4; ++rr) {
            float v = qsacc[kt][rr];
            v += __shfl_xor(v, 1);
            v += __shfl_xor(v, 2);
            v += __shfl_xor(v, 4);
            v += __shfl_xor(v, 8);
            if (r16 == 0) qsum_s[w][16 * kt + 4 * q + rr] = v;
        }
    __syncthreads();
    if (t < 64)
        part[t] = qsum_s[0][t] + qsum_s[1][t] + qsum_s[2][t] + qsum_s[3][t];
}

__global__ __launch_bounds__(256) void fv_finalize(const float* __restrict__ pi,
                                                   const float* __restrict__ mu,
                                                   const float* __restrict__ var,
                                                   const float* __restrict__ partials,
                                                   float* __restrict__ out,
                                                   int chunks) {
    int g = blockIdx.x * 256 + threadIdx.x;
    if (g >= B_ * OUT_PER_B) return;
    int b   = g / OUT_PER_B;
    int pos = g - b * OUT_PER_B;
    const float* base = partials + (size_t)b * chunks * PART_FLOATS;
    const float invN = 1.0f / (float)N_;

    if (pos < 64) {
        float qs = 0.0f;
        for (int c = 0; c < chunks; ++c) qs += base[c * PART_FLOATS + pos];
        out[g] = qs * invN - pi[pos];
    } else if (pos < 64 + 4096) {
        int idx = pos - 64;
        int k = idx >> 6;
        float qs = 0.0f, qx = 0.0f;
        for (int c = 0; c < chunks; ++c) {
            qs += base[c * PART_FLOATS + k];
            qx += base[c * PART_FLOATS + pos];
        }
        out[g] = (qx - qs * mu[idx]) * invN;
    } else {
        int idx = pos - 64 - 4096;
        int k = idx >> 6;
        float qs = 0.0f, qx = 0.0f, qx2 = 0.0f;
        for (int c = 0; c < chunks; ++c) {
            qs  += base[c * PART_FLOATS + k];
            qx  += base[c * PART_FLOATS + 64 + idx];
            qx2 += base[c * PART_FLOATS + pos];
        }
        float m = mu[idx], v = var[idx];
        out[g] = (-qx2 - qs * m * m + qs * v + 2.0f * qx * m) * invN;
    }
}

extern "C" void kernel_launch(void* const* d_in, const int* in_sizes, int n_in,
                              void* d_out, int out_size, void* d_ws, size_t ws_size,
                              hipStream_t stream) {
    const float* x   = (const float*)d_in[0];
    const float* pi  = (const float*)d_in[1];
    const float* mu  = (const float*)d_in[2];
    const float* var = (const float*)d_in[3];
    float* ws = (float*)d_ws;
    float* partials = ws + WS_PART_OFF;

    fv_prep<<<1, 256, 0, stream>>>(pi, mu, var, ws);
    fv_main<<<dim3(CHUNKS, B_), 256, 0, stream>>>(x, ws, partials);
    int total = B_ * OUT_PER_B;
    fv_finalize<<<(total + 255) / 256, 256, 0, stream>>>(pi, mu, var, partials,
                                                         (float*)d_out, CHUNKS);
}

// Round 6
// 120.587 us; speedup vs baseline: 1.8490x; 1.0635x over previous
//
#include <hip/hip_runtime.h>
#include <hip/hip_bf16.h>
#include <math.h>

// Problem constants (fixed by the reference).
#define B_  16
#define N_  16384
#define D_  64
#define K_  64
#define OUT_PER_B (K_ + 2*K_*D_)   // 8256
#define CHUNKS 32
#define NTILES (N_ / CHUNKS / 64)  // 8

// ws layout:
//   float[0,4096)    Wt bf16 [64 k][128 kd] as 8192 ushorts: kd<64 = -0.5/var, kd>=64 = mu/var
//   float[4096,4160) c0[k] = log(pi[k]) - 0.5*(D*log(2pi) + sum log var + sum mu^2/var)
//   byte region at WS_PART_OFF floats: per (b,chunk) partial record:
//     f32 qsum[64] | bf16 qx[64*64] | bf16 qx2[64*64]   (16640 B, stride PART_STRIDE)
#define WS_C0_OFF   4096
#define WS_PART_OFF 4160
#define PART_STRIDE (64*4 + 2*4096*2)   // 16640 bytes

typedef float f32x4 __attribute__((ext_vector_type(4)));
typedef short short8 __attribute__((ext_vector_type(8)));

union U8 { short8 s8; unsigned int u[4]; };

__device__ __forceinline__ unsigned short f2bf(float f) {
    union { float f; unsigned int u; } v; v.f = f;
    unsigned int r = v.u + 0x7FFFu + ((v.u >> 16) & 1u);   // round-to-nearest-even
    return (unsigned short)(r >> 16);
}

// packed RNE f32x2 -> bf16x2 (v_cvt_pk_bf16_f32 on gfx950)
__device__ __forceinline__ unsigned int f2bf2(float lo, float hi) {
    __hip_bfloat162 h = __float22bfloat162_rn(make_float2(lo, hi));
    unsigned int u;
    __builtin_memcpy(&u, &h, 4);
    return u;
}

__device__ __forceinline__ float bf2f(unsigned short u) {
    unsigned int v = ((unsigned int)u) << 16;
    float f;
    __builtin_memcpy(&f, &v, 4);
    return f;
}

__global__ __launch_bounds__(256) void fv_prep(const float* __restrict__ pi,
                                               const float* __restrict__ mu,
                                               const float* __restrict__ var,
                                               float* __restrict__ ws) {
    __shared__ float red[256];
    int t = threadIdx.x;
    unsigned short* wt = (unsigned short*)ws;
    for (int i = t; i < 4096; i += 256) {        // i = k*64 + d
        int k = i >> 6, d = i & 63;
        float v  = var[i];
        float m  = mu[i];
        float iv = 1.0f / v;
        wt[k * 128 + d]      = f2bf(-0.5f * iv);
        wt[k * 128 + 64 + d] = f2bf(m * iv);
    }
    // c0: 4 threads per k, 16 dims each
    int k = t >> 2, pr = t & 3;
    float s = 0.0f;
    #pragma unroll
    for (int j = 0; j < 16; ++j) {
        int d = pr * 16 + j;
        float v = var[k * 64 + d];
        float m = mu[k * 64 + d];
        s += __logf(v) + m * m / v;
    }
    red[t] = s;
    __syncthreads();
    if (pr == 0) {
        float sum = red[4 * k] + red[4 * k + 1] + red[4 * k + 2] + red[4 * k + 3];
        // D*log(2*pi) = 117.6241322501981
        ws[WS_C0_OFF + k] = __logf(pi[k]) - 0.5f * (117.6241322502f + sum);
    }
}

// MFMA layouts (16x16x32 bf16, guide-verified):
//   A[m = lane&15][kk = (lane>>4)*8 + j]
//   B[kk = (lane>>4)*8 + j][n = lane&15]
//   C/D: col = lane&15, row = 4*(lane>>4) + reg
__global__ __launch_bounds__(256, 2) void fv_main(const float* __restrict__ x,
                                                  const float* __restrict__ ws,
                                                  char* __restrict__ partials) {
    __shared__ __align__(16) unsigned short QtS[2][64 * 72];  // double-buffered Q^T[k][p]
    __shared__ float qsum_s[4][64];

    const int t    = threadIdx.x;
    const int w    = t >> 6;        // wave 0..3
    const int lane = t & 63;
    const int r16  = lane & 15;
    const int q    = lane >> 4;     // quad 0..3

    // ---- tile-invariant operands -> registers ----
    short8 wfrag[4][4];             // [kt][half]: A-fragments of Wt
    f32x4  c0v[4];
    {
        const unsigned short* wsu = (const unsigned short*)ws;
        #pragma unroll
        for (int kt = 0; kt < 4; ++kt) {
            const unsigned short* wr = wsu + (16 * kt + r16) * 128 + 8 * q;
            #pragma unroll
            for (int h = 0; h < 4; ++h)
                wfrag[kt][h] = *(const short8*)(const void*)(wr + 32 * h);
            c0v[kt] = *(const f32x4*)(ws + WS_C0_OFF + 16 * kt + 4 * q);
        }
    }

    const int bi    = blockIdx.y;
    const int chunk = blockIdx.x;
    const int ppb   = N_ / CHUNKS;
    const float* xb = x + ((size_t)bi * N_ + (size_t)chunk * ppb) * D_;

    f32x4 accX[4]  = {};       // Qx  : k rows, d col = 16w + r16
    f32x4 accX2[4] = {};       // Qx2
    float qsacc[4][4] = {};    // per-lane Q sums (ks: 16kt + 4q + rr)

    const int rowoff = (16 * w + r16) * D_ + 8 * q;   // phase-1 row base
    const int dcol   = 16 * w + r16;                  // phase-2 column

    // ---- preload tile-0 phase-1 rows ----
    float4 va, vb, vc, vd;
    {
        const float* xr = xb + rowoff;
        va = *(const float4*)(xr);
        vb = *(const float4*)(xr + 4);
        vc = *(const float4*)(xr + 32);
        vd = *(const float4*)(xr + 36);
    }

    #pragma unroll 2
    for (int tile = 0; tile < NTILES; ++tile) {
        const float* xt = xb + (size_t)tile * 64 * D_;

        // ---- prefetch next tile's rows (stays in flight across the manual barrier) ----
        float4 nva, nvb, nvc, nvd;
        if (tile + 1 < NTILES) {
            const float* xr = xt + 64 * D_ + rowoff;
            nva = *(const float4*)(xr);
            nvb = *(const float4*)(xr + 4);
            nvc = *(const float4*)(xr + 32);
            nvd = *(const float4*)(xr + 36);
        }

        // ================= phase 1: S^T[k][p] =================
        U8 fxa, fxb, fx2a, fx2b;
        fxa.u[0]  = f2bf2(va.x, va.y);           fxa.u[1]  = f2bf2(va.z, va.w);
        fxa.u[2]  = f2bf2(vb.x, vb.y);           fxa.u[3]  = f2bf2(vb.z, vb.w);
        fxb.u[0]  = f2bf2(vc.x, vc.y);           fxb.u[1]  = f2bf2(vc.z, vc.w);
        fxb.u[2]  = f2bf2(vd.x, vd.y);           fxb.u[3]  = f2bf2(vd.z, vd.w);
        fx2a.u[0] = f2bf2(va.x*va.x, va.y*va.y); fx2a.u[1] = f2bf2(va.z*va.z, va.w*va.w);
        fx2a.u[2] = f2bf2(vb.x*vb.x, vb.y*vb.y); fx2a.u[3] = f2bf2(vb.z*vb.z, vb.w*vb.w);
        fx2b.u[0] = f2bf2(vc.x*vc.x, vc.y*vc.y); fx2b.u[1] = f2bf2(vc.z*vc.z, vc.w*vc.w);
        fx2b.u[2] = f2bf2(vd.x*vd.x, vd.y*vd.y); fx2b.u[3] = f2bf2(vd.z*vd.z, vd.w*vd.w);

        float sc[4][4];
        #pragma unroll
        for (int kt = 0; kt < 4; ++kt) {
            f32x4 a = c0v[kt];
            a = __builtin_amdgcn_mfma_f32_16x16x32_bf16(wfrag[kt][0], fx2a.s8, a, 0, 0, 0);
            a = __builtin_amdgcn_mfma_f32_16x16x32_bf16(wfrag[kt][1], fx2b.s8, a, 0, 0, 0);
            a = __builtin_amdgcn_mfma_f32_16x16x32_bf16(wfrag[kt][2], fxa.s8,  a, 0, 0, 0);
            a = __builtin_amdgcn_mfma_f32_16x16x32_bf16(wfrag[kt][3], fxb.s8,  a, 0, 0, 0);
            sc[kt][0] = a[0]; sc[kt][1] = a[1]; sc[kt][2] = a[2]; sc[kt][3] = a[3];
        }

        // ---- softmax over k: 16 in-lane values + lanes^16,^32 (same point p) ----
        float mx = sc[0][0];
        #pragma unroll
        for (int kt = 0; kt < 4; ++kt)
            #pragma unroll
            for (int rr = 0; rr < 4; ++rr) mx = fmaxf(mx, sc[kt][rr]);
        mx = fmaxf(mx, __shfl_xor(mx, 16));
        mx = fmaxf(mx, __shfl_xor(mx, 32));
        float z = 0.0f;
        #pragma unroll
        for (int kt = 0; kt < 4; ++kt)
            #pragma unroll
            for (int rr = 0; rr < 4; ++rr) {
                sc[kt][rr] = __expf(sc[kt][rr] - mx);
                z += sc[kt][rr];
            }
        z += __shfl_xor(z, 16);
        z += __shfl_xor(z, 32);
        float inv = 1.0f / z;
        const int p = 16 * w + r16;
        unsigned short* Qb = QtS[tile & 1];
        #pragma unroll
        for (int kt = 0; kt < 4; ++kt) {
            #pragma unroll
            for (int rr = 0; rr < 4; rr += 2) {
                float q0 = sc[kt][rr] * inv;
                float q1 = sc[kt][rr + 1] * inv;
                qsacc[kt][rr]     += q0;
                qsacc[kt][rr + 1] += q1;
                unsigned int pk = f2bf2(q0, q1);
                Qb[(16 * kt + 4 * q + rr)     * 72 + p] = (unsigned short)pk;
                Qb[(16 * kt + 4 * q + rr + 1) * 72 + p] = (unsigned short)(pk >> 16);
            }
        }

        // ---- phase-2 column loads for CURRENT tile (L1/L2-hot; in flight across barrier) ----
        float vle[16];
        {
            const float* xc = xt + dcol;
            #pragma unroll
            for (int c = 0; c < 2; ++c)
                #pragma unroll
                for (int j = 0; j < 8; ++j)
                    vle[8 * c + j] = xc[(32 * c + 8 * q + j) * D_];
        }

        // barrier WITHOUT vmcnt(0) drain (LDS visibility only) — keeps prefetches in flight
        asm volatile("s_waitcnt lgkmcnt(0)\n\ts_barrier" ::: "memory");

        // ================= phase 2: Qx[k][d], Qx2[k][d] =================
        U8 fxp0, fxp1, fx2p0, fx2p1;
        #pragma unroll
        for (int i = 0; i < 4; ++i) {
            float a0 = vle[2 * i], a1 = vle[2 * i + 1];
            float b0 = vle[8 + 2 * i], b1 = vle[8 + 2 * i + 1];
            fxp0.u[i]  = f2bf2(a0, a1);
            fxp1.u[i]  = f2bf2(b0, b1);
            fx2p0.u[i] = f2bf2(a0 * a0, a1 * a1);
            fx2p1.u[i] = f2bf2(b0 * b0, b1 * b1);
        }
        #pragma unroll
        for (int kt = 0; kt < 4; ++kt) {
            const unsigned short* qr = &Qb[(16 * kt + r16) * 72 + 8 * q];
            short8 aq0 = *(const short8*)(const void*)(qr);
            short8 aq1 = *(const short8*)(const void*)(qr + 32);
            accX[kt]  = __builtin_amdgcn_mfma_f32_16x16x32_bf16(aq0, fxp0.s8,  accX[kt],  0, 0, 0);
            accX2[kt] = __builtin_amdgcn_mfma_f32_16x16x32_bf16(aq0, fx2p0.s8, accX2[kt], 0, 0, 0);
            accX[kt]  = __builtin_amdgcn_mfma_f32_16x16x32_bf16(aq1, fxp1.s8,  accX[kt],  0, 0, 0);
            accX2[kt] = __builtin_amdgcn_mfma_f32_16x16x32_bf16(aq1, fx2p1.s8, accX2[kt], 0, 0, 0);
        }

        // rotate pipeline registers (renamed away by unroll)
        va = nva; vb = nvb; vc = nvc; vd = nvd;
    }

    // ---- write partials: f32 qsum[64] | bf16 qx[4096] | bf16 qx2[4096] ----
    char* rec = partials + ((size_t)bi * CHUNKS + chunk) * PART_STRIDE;
    float* part_qs = (float*)rec;
    unsigned short* part_qx  = (unsigned short*)(rec + 256);
    unsigned short* part_qx2 = part_qx + 4096;
    #pragma unroll
    for (int kt = 0; kt < 4; ++kt)
        #pragma unroll
        for (int rr = 0; rr < 4; ++rr) {
            int k = 16 * kt + 4 * q + rr;
            part_qx [k * 64 + 16 * w + r16] = f2bf(accX[kt][rr]);
            part_qx2[k * 64 + 16 * w + r16] = f2bf(accX2[kt][rr]);
        }
    #pragma unroll
    for (int kt = 0; kt < 4; ++kt)
        #pragma unroll
        for (int rr = 0; rr < 4; ++rr) {
            float v = qsacc[kt][rr];
            v += __shfl_xor(v, 1);
            v += __shfl_xor(v, 2);
            v += __shfl_xor(v, 4);
            v += __shfl_xor(v, 8);
            if (r16 == 0) qsum_s[w][16 * kt + 4 * q + rr] = v;
        }
    __syncthreads();
    if (t < 64)
        part_qs[t] = qsum_s[0][t] + qsum_s[1][t] + qsum_s[2][t] + qsum_s[3][t];
}

__global__ __launch_bounds__(256) void fv_finalize(const float* __restrict__ pi,
                                                   const float* __restrict__ mu,
                                                   const float* __restrict__ var,
                                                   const char* __restrict__ partials,
                                                   float* __restrict__ out) {
    int g = blockIdx.x * 256 + threadIdx.x;
    if (g >= B_ * OUT_PER_B) return;
    int b   = g / OUT_PER_B;
    int pos = g - b * OUT_PER_B;
    const char* base = partials + (size_t)b * CHUNKS * PART_STRIDE;
    const float invN = 1.0f / (float)N_;

    if (pos < 64) {
        float qs = 0.0f;
        for (int c = 0; c < CHUNKS; ++c)
            qs += ((const float*)(base + c * PART_STRIDE))[pos];
        out[g] = qs * invN - pi[pos];
    } else if (pos < 64 + 4096) {
        int idx = pos - 64;
        int k = idx >> 6;
        float qs = 0.0f, qx = 0.0f;
        for (int c = 0; c < CHUNKS; ++c) {
            const char* r = base + c * PART_STRIDE;
            qs += ((const float*)r)[k];
            qx += bf2f(((const unsigned short*)(r + 256))[idx]);
        }
        out[g] = (qx - qs * mu[idx]) * invN;
    } else {
        int idx = pos - 64 - 4096;
        int k = idx >> 6;
        float qs = 0.0f, qx = 0.0f, qx2 = 0.0f;
        for (int c = 0; c < CHUNKS; ++c) {
            const char* r = base + c * PART_STRIDE;
            qs  += ((const float*)r)[k];
            qx  += bf2f(((const unsigned short*)(r + 256))[idx]);
            qx2 += bf2f(((const unsigned short*)(r + 256))[4096 + idx]);
        }
        float m = mu[idx], v = var[idx];
        out[g] = (-qx2 - qs * m * m + qs * v + 2.0f * qx * m) * invN;
    }
}

extern "C" void kernel_launch(void* const* d_in, const int* in_sizes, int n_in,
                              void* d_out, int out_size, void* d_ws, size_t ws_size,
                              hipStream_t stream) {
    const float* x   = (const float*)d_in[0];
    const float* pi  = (const float*)d_in[1];
    const float* mu  = (const float*)d_in[2];
    const float* var = (const float*)d_in[3];
    float* ws = (float*)d_ws;
    char* partials = (char*)(ws + WS_PART_OFF);

    fv_prep<<<1, 256, 0, stream>>>(pi, mu, var, ws);
    fv_main<<<dim3(CHUNKS, B_), 256, 0, stream>>>(x, ws, partials);
    int total = B_ * OUT_PER_B;
    fv_finalize<<<(total + 255) / 256, 256, 0, stream>>>(pi, mu, var, partials,
                                                         (float*)d_out);
}